// Round 4
// baseline (274.745 us; speedup 1.0000x reference)
//
#include <hip/hip_runtime.h>
#include <float.h>
#include <math.h>

#define BATCH 8
#define CHN   128
#define NPTS  2048
#define KNN   9
#define NOUT  256
#define TOTCNT (BATCH*NPTS*KNN)

typedef __attribute__((ext_vector_type(8))) short short8;
typedef __attribute__((ext_vector_type(4))) float f32x4;

__device__ __forceinline__ unsigned short f2bf(float f) {
    unsigned int u = __float_as_uint(f);
    unsigned int r = (u + 0x7FFFu + ((u >> 16) & 1u)) >> 16;
    return (unsigned short)r;
}
__device__ __forceinline__ float bf2f(unsigned short h) {
    return __uint_as_float(((unsigned int)h) << 16);
}

// ---------------- kernel 1: transpose + bf16 split + 0.5*sqnorm (+ W split + stats zero) ----------------
__global__ __launch_bounds__(256) void prep_kernel(const float* __restrict__ x,
                                                   const float* __restrict__ W,
                                                   unsigned short* __restrict__ xhi,
                                                   unsigned short* __restrict__ xlo,
                                                   unsigned short* __restrict__ whi,
                                                   unsigned short* __restrict__ wlo,
                                                   float* __restrict__ sqh,
                                                   float* __restrict__ stats) {
    __shared__ float xt[128 * 65];
    __shared__ float psq[256];
    const int b = blockIdx.x, tid = threadIdx.x;
    if (blockIdx.y == 32) {   // W -> Bcat=[W1-W2; W2] hi/lo split + zero this batch's stats copy
        stats[b * 512 + tid] = 0.f;
        stats[b * 512 + 256 + tid] = 0.f;
#pragma unroll
        for (int e = 0; e < 32; ++e) {
            int idx = e * 256 + tid;
            int r = b * 64 + (idx >> 7), c = idx & 127;
            float v = (r < 256) ? (W[r * 256 + c] - W[r * 256 + 128 + c])
                                : W[(r - 256) * 256 + 128 + c];
            unsigned short h = f2bf(v);
            float hf = bf2f(h);
            whi[r * 128 + c] = h;
            wlo[r * 128 + c] = f2bf(v - hf);
        }
        return;
    }
    const int n0 = blockIdx.y * 64;
#pragma unroll 4
    for (int p = 0; p < 32; ++p) {
        int c = p * 4 + (tid >> 6), n = tid & 63;
        xt[c * 65 + n] = x[((size_t)b * CHN + c) * NPTS + n0 + n];
    }
    __syncthreads();
    const int n = tid >> 2, cq = tid & 3;
    size_t row = (size_t)(b * NPTS + n0 + n) * CHN;
    float s = 0.f;
#pragma unroll 8
    for (int j = 0; j < 32; ++j) {
        int c = cq * 32 + j;
        float f = xt[c * 65 + n];
        unsigned short h = f2bf(f);
        float hf = bf2f(h);
        unsigned short l = f2bf(f - hf);
        xhi[row + c] = h;
        xlo[row + c] = l;
        s += f * f;
    }
    psq[tid] = s;
    __syncthreads();
    if (tid < 64)
        sqh[b * NPTS + n0 + tid] =
            0.5f * (psq[tid*4] + psq[tid*4+1] + psq[tid*4+2] + psq[tid*4+3]);
}

// ---------------- kernel 2: knn + pq, z-parity roles; knn = REGISTER-DIRECT (R4 operand swap) -----------
// R3 post-mortem: per-iter LDS transpose (dump 32 ds_write -> lgkmcnt drain -> 8 ds_read_b128 ->
// serial fmin) was the non-overlappable chain; all pipes <45%. R4: swap MFMA operands: D = M x Q^T,
// so D col (lane&15) = QUERY. Wave wv owns 16 queries (B-frag, both planes in 32 VGPRs) and streams
// ALL 512 m of the slice as A-frags (8 chunks x 64 m). acc[i][r] is directly the lane's own query's
// distance to m = ch*64 + i*16 + quad*4 + r -> top-9 insert runs on registers. Quads partition
// m mod 16; final merge = 2 shfl_xor rounds (16,32) + tie-aware insert, once. ZERO LDS, ZERO barriers,
// ZERO per-iter DS ops. m loaded by all 4 waves (L1 absorbs lockstep reuse; L2 affinity via b fastest).
__global__ __launch_bounds__(256, 4) void knnpq_mfma(const unsigned short* __restrict__ xhi,
                                                  const unsigned short* __restrict__ xlo,
                                                  const float* __restrict__ sqh,
                                                  const unsigned short* __restrict__ whi,
                                                  const unsigned short* __restrict__ wlo,
                                                  float* __restrict__ pd,
                                                  int* __restrict__ pi,
                                                  float* __restrict__ p,
                                                  unsigned short* __restrict__ q) {
    const int tid = threadIdx.x;
    const int b  = blockIdx.x;          // batch fastest -> XCD k serves batch k (L2 affinity)
    const int zr = blockIdx.z;
    const int sub = zr >> 1;            // 0..3 within role
    const int wv = tid >> 6, lane = tid & 63;
    const int quad = lane >> 4, col = lane & 15;
    const int koff = quad * 8;
    const size_t xb = (size_t)b * NPTS * CHN;

    if (zr & 1) {
        // ---------------- pq path: 256n x 32o per block, acc[4][2] per wave (R15-proven) ----------------
        const int nt = blockIdx.y >> 2;
        const int ot = ((blockIdx.y & 3) << 2) | sub;                 // 0..15
        const int nbase = nt * 256 + wv * 64;
        const int obase = ot * 32;                                    // row in Bcat [512]

        f32x4 acc[4][2];
#pragma unroll
        for (int i = 0; i < 4; ++i)
#pragma unroll
            for (int j = 0; j < 2; ++j) acc[i][j] = (f32x4)0.f;

        for (int chk = 0; chk < 4; ++chk) {
            short8 ah[4], al[4];
#pragma unroll
            for (int i = 0; i < 4; ++i) {
                size_t g = xb + (size_t)(nbase + i * 16 + col) * CHN + chk * 32 + koff;
                ah[i] = *(const short8*)&xhi[g];
                al[i] = *(const short8*)&xlo[g];
            }
#pragma unroll
            for (int j = 0; j < 2; ++j) {
                size_t g = (size_t)(obase + j * 16 + col) * CHN + chk * 32 + koff;
                short8 bh = *(const short8*)&whi[g];
                short8 bl = *(const short8*)&wlo[g];
#pragma unroll
                for (int i = 0; i < 4; ++i) {
                    acc[i][j] = __builtin_amdgcn_mfma_f32_16x16x32_bf16(ah[i], bh, acc[i][j], 0, 0, 0);
                    acc[i][j] = __builtin_amdgcn_mfma_f32_16x16x32_bf16(ah[i], bl, acc[i][j], 0, 0, 0);
                    acc[i][j] = __builtin_amdgcn_mfma_f32_16x16x32_bf16(al[i], bh, acc[i][j], 0, 0, 0);
                }
            }
        }
#pragma unroll
        for (int i = 0; i < 4; ++i)
#pragma unroll
            for (int j = 0; j < 2; ++j) {
                int oc = (obase + j * 16 + col) & 255;
#pragma unroll
                for (int r = 0; r < 4; ++r) {
                    int n = nbase + i * 16 + quad * 4 + r;
                    size_t off = (size_t)(b * NPTS + n) * NOUT + oc;
                    if (ot < 8) p[off] = acc[i][j][r];
                    else        q[off] = f2bf(acc[i][j][r]);
                }
            }
        return;
    }

    // ---------------- knn path (register-direct) ----------------
    const int q0 = blockIdx.y * 64, ms = sub;
    const int msbase = ms * 512;
    const int myq = q0 + wv * 16 + col;           // this lane's query (D col = lane&15 = B col)

    // query B-frags, both planes, resident in 32 VGPRs
    short8 qh[4], ql[4];
    {
        const unsigned short* qrh = xhi + xb + (size_t)myq * CHN + koff;
        const unsigned short* qrl = xlo + xb + (size_t)myq * CHN + koff;
#pragma unroll
        for (int chk = 0; chk < 4; ++chk) {
            qh[chk] = *(const short8*)(qrh + chk * 32);
            ql[chk] = *(const short8*)(qrl + chk * 32);
        }
    }

    float dl[KNN]; int il[KNN];
#pragma unroll
    for (int k = 0; k < KNN; ++k) { dl[k] = FLT_MAX; il[k] = 0; }

    // scan insert: strict < (candidates arrive in ascending m -> ties keep earlier idx)
    auto ins = [&](float v, int idx) {
        if (v < dl[KNN - 1]) {
            bool c0b = v < dl[0];
#pragma unroll
            for (int k = KNN - 1; k >= 1; --k) {
                bool sh   = v < dl[k - 1];
                bool here = v < dl[k];
                float nd = sh ? dl[k - 1] : (here ? v : dl[k]);
                int   ni = sh ? il[k - 1] : (here ? idx : il[k]);
                dl[k] = nd; il[k] = ni;
            }
            if (c0b) { dl[0] = v; il[0] = idx; }
        }
    };
    // merge insert: tie-aware (smaller m-idx wins on equal value)
    auto ins2 = [&](float v, int idx) {
        if ((v < dl[KNN - 1]) || (v == dl[KNN - 1] && idx < il[KNN - 1])) {
            bool c0b = (v < dl[0]) || (v == dl[0] && idx < il[0]);
#pragma unroll
            for (int k = KNN - 1; k >= 1; --k) {
                bool sh   = (v < dl[k - 1]) || (v == dl[k - 1] && idx < il[k - 1]);
                bool here = (v < dl[k])     || (v == dl[k]     && idx < il[k]);
                float nd = sh ? dl[k - 1] : (here ? v : dl[k]);
                int   ni = sh ? il[k - 1] : (here ? idx : il[k]);
                dl[k] = nd; il[k] = ni;
            }
            if (c0b) { dl[0] = v; il[0] = idx; }
        }
    };

    const unsigned short* mbh = xhi + xb + (size_t)(msbase + col) * CHN + koff;
    const unsigned short* mbl = xlo + xb + (size_t)(msbase + col) * CHN + koff;
    const float* smb = sqh + b * NPTS + msbase + quad * 4;

    for (int ch = 0; ch < 8; ++ch) {
        f32x4 acc[4];
#pragma unroll
        for (int i = 0; i < 4; ++i) acc[i] = (f32x4)0.f;

#pragma unroll
        for (int chk = 0; chk < 4; ++chk) {
            short8 mh[4], ml[4];
#pragma unroll
            for (int i = 0; i < 4; ++i) {
                const int ro = i * 16 * CHN + chk * 32;     // element offset (compile-time)
                mh[i] = *(const short8*)(mbh + ro);
                ml[i] = *(const short8*)(mbl + ro);
            }
#pragma unroll
            for (int i = 0; i < 4; ++i) {
                acc[i] = __builtin_amdgcn_mfma_f32_16x16x32_bf16(mh[i], qh[chk], acc[i], 0, 0, 0);
                acc[i] = __builtin_amdgcn_mfma_f32_16x16x32_bf16(mh[i], ql[chk], acc[i], 0, 0, 0);
                acc[i] = __builtin_amdgcn_mfma_f32_16x16x32_bf16(ml[i], qh[chk], acc[i], 0, 0, 0);
            }
        }

        const int mb0 = ch << 6;
#pragma unroll
        for (int i = 0; i < 4; ++i) {
            float4 sm = *(const float4*)(smb + mb0 + i * 16);
            float d0 = sm.x - acc[i][0], d1 = sm.y - acc[i][1];
            float d2 = sm.z - acc[i][2], d3 = sm.w - acc[i][3];
            float mn4 = fminf(fminf(d0, d1), fminf(d2, d3));
            if (mn4 < dl[KNN - 1]) {
                int ib = msbase + mb0 + i * 16 + quad * 4;
                ins(d0, ib); ins(d1, ib + 1); ins(d2, ib + 2); ins(d3, ib + 3);
            }
        }
        mbh += 64 * CHN;
        mbl += 64 * CHN;
    }

    // cross-quad merge: quads partition m mod 16; 2 butterfly rounds leave full top-9 in every lane
#pragma unroll
    for (int rd = 0; rd < 2; ++rd) {
        const int xm = 16 << rd;
        float pv[KNN]; int pix[KNN];
#pragma unroll
        for (int k = 0; k < KNN; ++k) {
            pv[k]  = __shfl_xor(dl[k], xm, 64);
            pix[k] = __shfl_xor(il[k], xm, 64);
        }
#pragma unroll
        for (int k = 0; k < KNN; ++k) ins2(pv[k], pix[k]);
    }

    if (quad == 0) {
        size_t ob = ((size_t)(b * NPTS + myq) * 4 + ms) * KNN;
#pragma unroll
        for (int k = 0; k < KNN; ++k) {
            pd[ob + k] = dl[k];
            pi[ob + k] = il[k];
        }
    }
}

// ---------------- kernel 3: merge FUSED + BN stats + packed bf16 (hmax,hmin); 512 thr (R3) ---------------
__global__ __launch_bounds__(512) void stats2_kernel(const float* __restrict__ p,
                                                     const unsigned short* __restrict__ q,
                                                     const float* __restrict__ pd,
                                                     const int* __restrict__ pi,
                                                     float* __restrict__ stats,
                                                     unsigned int* __restrict__ hmm) {
    __shared__ int idx_s[16 * KNN];
    const int b = blockIdx.x, n0 = blockIdx.y * 16;
    const int tid = threadIdx.x;
    const int o = tid & 255, half = tid >> 8;
    if (tid < 16) {
        size_t g = (size_t)(b * NPTS + n0 + tid) * 36;
        const float* d = pd + g;
        const int*   i = pi + g;
        int p0 = 0, p1 = 0, p2 = 0, p3 = 0;
#pragma unroll
        for (int k = 0; k < KNN; ++k) {
            float v0 = (p0 < KNN) ? d[p0]      : FLT_MAX;
            float v1 = (p1 < KNN) ? d[9 + p1]  : FLT_MAX;
            float v2 = (p2 < KNN) ? d[18 + p2] : FLT_MAX;
            float v3 = (p3 < KNN) ? d[27 + p3] : FLT_MAX;
            float best = v0; int sel = 0;
            if (v1 < best) { best = v1; sel = 1; }
            if (v2 < best) { best = v2; sel = 2; }
            if (v3 < best) { best = v3; sel = 3; }
            int idx;
            if      (sel == 0) { idx = i[p0];      p0++; }
            else if (sel == 1) { idx = i[9 + p1];  p1++; }
            else if (sel == 2) { idx = i[18 + p2]; p2++; }
            else               { idx = i[27 + p3]; p3++; }
            idx_s[tid * KNN + k] = idx;
        }
    }
    __syncthreads();
    const unsigned short* qb = q + (size_t)b * NPTS * NOUT + o;
    float s = 0.f, ss = 0.f;
    const int qbase = half * 8;
    for (int qq = 0; qq < 8; qq += 2) {
        const int qi = qbase + qq;
        size_t off0 = (size_t)(b * NPTS + n0 + qi) * NOUT + o;
        size_t off1 = off0 + NOUT;
        float pv0 = p[off0], pv1 = p[off1];
        float h0[KNN], h1[KNN];
#pragma unroll
        for (int k = 0; k < KNN; ++k)
            h0[k] = bf2f(qb[(size_t)idx_s[qi * KNN + k] * NOUT]);
#pragma unroll
        for (int k = 0; k < KNN; ++k)
            h1[k] = bf2f(qb[(size_t)idx_s[(qi + 1) * KNN + k] * NOUT]);
        float mx0 = -FLT_MAX, mn0 = FLT_MAX, mx1 = -FLT_MAX, mn1 = FLT_MAX;
#pragma unroll
        for (int k = 0; k < KNN; ++k) {
            float a = pv0 + h0[k], c = pv1 + h1[k];
            s += a + c; ss += a * a + c * c;
            mx0 = fmaxf(mx0, a); mn0 = fminf(mn0, a);
            mx1 = fmaxf(mx1, c); mn1 = fminf(mn1, c);
        }
        hmm[off0] = ((unsigned int)f2bf(mx0) << 16) | f2bf(mn0);
        hmm[off1] = ((unsigned int)f2bf(mx1) << 16) | f2bf(mn1);
    }
    atomicAdd(&stats[b * 512 + o], s);
    atomicAdd(&stats[b * 512 + NOUT + o], ss);
}

// ---------------- kernel 4: normalize + relu + max_k, transposed store; 512 thr (R3) ----------------
__global__ __launch_bounds__(512) void final_kernel(const unsigned int* __restrict__ hmm,
                                                    const float* __restrict__ stats,
                                                    const float* __restrict__ gamma,
                                                    const float* __restrict__ beta,
                                                    float* __restrict__ out) {
    __shared__ float tr[256 * 17];
    const int b = blockIdx.x, n0 = blockIdx.y * 16;
    const int tid = threadIdx.x;
    const int o = tid & 255, qh = tid >> 8;
    float sum = 0.f, sumsq = 0.f;
#pragma unroll
    for (int i = 0; i < 8; ++i) {
        sum   += stats[i * 512 + o];
        sumsq += stats[i * 512 + NOUT + o];
    }
    const float inv = 1.f / (float)TOTCNT;
    float mean = sum * inv;
    float var  = sumsq * inv - mean * mean;
    float g    = gamma[o] / sqrtf(var + 1e-5f);
    float bet  = beta[o];
    const bool pos = (g >= 0.f);
#pragma unroll
    for (int qq = 0; qq < 8; ++qq) {
        const int qi = qh * 8 + qq;
        size_t off = (size_t)(b * NPTS + n0 + qi) * NOUT + o;
        unsigned int w = hmm[off];
        float v = bf2f(pos ? (unsigned short)(w >> 16) : (unsigned short)(w & 0xFFFFu));
        float hn = (v - mean) * g + bet;
        tr[o * 17 + qi] = fmaxf(hn, 0.f);
    }
    __syncthreads();
    int oo = tid >> 4, qq = tid & 15;    // oo 0..31
    for (int pass = 0; pass < 8; ++pass) {
        int o_ = pass * 32 + oo;
        out[((size_t)b * NOUT + o_) * NPTS + n0 + qq] = tr[o_ * 17 + qq];
    }
}

extern "C" void kernel_launch(void* const* d_in, const int* in_sizes, int n_in,
                              void* d_out, int out_size, void* d_ws, size_t ws_size,
                              hipStream_t stream) {
    (void)in_sizes; (void)n_in; (void)out_size; (void)ws_size;
    const float* x     = (const float*)d_in[0];
    const float* W     = (const float*)d_in[1];
    const float* gamma = (const float*)d_in[2];
    const float* beta  = (const float*)d_in[3];
    float* out = (float*)d_out;

    char* ws = (char*)d_ws;
    float*          p     = (float*)ws;                                   // 16 MB fp32
    unsigned short* q     = (unsigned short*)(ws + (16u << 20));          // 8 MB bf16
    unsigned short* xhi   = (unsigned short*)(ws + (24u << 20));          // 4 MB
    unsigned short* xlo   = (unsigned short*)(ws + (28u << 20));          // 4 MB
    unsigned int*   hmm   = (unsigned int*)(ws + (32u << 20));            // 16 MB
    unsigned short* whi   = (unsigned short*)(ws + (48u << 20));          // 128 KB
    unsigned short* wlo   = (unsigned short*)(ws + (48u << 20) + 131072); // 128 KB
    float*          pd    = (float*)(ws + (49u << 20));                   // 2.25 MB
    int*            pi    = (int*)  (ws + (52u << 20));                   // 2.25 MB
    float*          sqh   = (float*)(ws + (55u << 20));                   // 64 KB
    float*          stats = (float*)(ws + (55u << 20) + 65536);           // 16 KB

    prep_kernel  <<<dim3(8, 33),    256, 0, stream>>>(x, W, xhi, xlo, whi, wlo, sqh, stats);
    knnpq_mfma   <<<dim3(8, 32, 8), 256, 0, stream>>>(xhi, xlo, sqh, whi, wlo, pd, pi, p, q);
    stats2_kernel<<<dim3(8, 128),   512, 0, stream>>>(p, q, pd, pi, stats, hmm);
    final_kernel <<<dim3(8, 128),   512, 0, stream>>>(hmm, stats, gamma, beta, out);
}

// Round 5
// 209.452 us; speedup vs baseline: 1.3117x; 1.3117x over previous
//
#include <hip/hip_runtime.h>
#include <float.h>
#include <math.h>

#define BATCH 8
#define CHN   128
#define NPTS  2048
#define KNN   9
#define NOUT  256
#define TOTCNT (BATCH*NPTS*KNN)

typedef __attribute__((ext_vector_type(8))) short short8;
typedef __attribute__((ext_vector_type(4))) float f32x4;

__device__ __forceinline__ unsigned short f2bf(float f) {
    unsigned int u = __float_as_uint(f);
    unsigned int r = (u + 0x7FFFu + ((u >> 16) & 1u)) >> 16;
    return (unsigned short)r;
}
__device__ __forceinline__ float bf2f(unsigned short h) {
    return __uint_as_float(((unsigned int)h) << 16);
}

// ---------------- kernel 1: transpose + bf16 split + 0.5*sqnorm (+ W split + stats zero) ----------------
__global__ __launch_bounds__(256) void prep_kernel(const float* __restrict__ x,
                                                   const float* __restrict__ W,
                                                   unsigned short* __restrict__ xhi,
                                                   unsigned short* __restrict__ xlo,
                                                   unsigned short* __restrict__ whi,
                                                   unsigned short* __restrict__ wlo,
                                                   float* __restrict__ sqh,
                                                   float* __restrict__ stats) {
    __shared__ float xt[128 * 65];
    __shared__ float psq[256];
    const int b = blockIdx.x, tid = threadIdx.x;
    if (blockIdx.y == 32) {   // W -> Bcat=[W1-W2; W2] hi/lo split + zero this batch's stats copy
        stats[b * 512 + tid] = 0.f;
        stats[b * 512 + 256 + tid] = 0.f;
#pragma unroll
        for (int e = 0; e < 32; ++e) {
            int idx = e * 256 + tid;
            int r = b * 64 + (idx >> 7), c = idx & 127;
            float v = (r < 256) ? (W[r * 256 + c] - W[r * 256 + 128 + c])
                                : W[(r - 256) * 256 + 128 + c];
            unsigned short h = f2bf(v);
            float hf = bf2f(h);
            whi[r * 128 + c] = h;
            wlo[r * 128 + c] = f2bf(v - hf);
        }
        return;
    }
    const int n0 = blockIdx.y * 64;
#pragma unroll 4
    for (int p = 0; p < 32; ++p) {
        int c = p * 4 + (tid >> 6), n = tid & 63;
        xt[c * 65 + n] = x[((size_t)b * CHN + c) * NPTS + n0 + n];
    }
    __syncthreads();
    const int n = tid >> 2, cq = tid & 3;
    size_t row = (size_t)(b * NPTS + n0 + n) * CHN;
    float s = 0.f;
#pragma unroll 8
    for (int j = 0; j < 32; ++j) {
        int c = cq * 32 + j;
        float f = xt[c * 65 + n];
        unsigned short h = f2bf(f);
        float hf = bf2f(h);
        unsigned short l = f2bf(f - hf);
        xhi[row + c] = h;
        xlo[row + c] = l;
        s += f * f;
    }
    psq[tid] = s;
    __syncthreads();
    if (tid < 64)
        sqh[b * NPTS + n0 + tid] =
            0.5f * (psq[tid*4] + psq[tid*4+1] + psq[tid*4+2] + psq[tid*4+3]);
}

// ---------------- kernel 2: knn + pq; knn = register-direct scan + LDS-SHARED m-stream (R5) -------------
// R4 post-mortem: register-direct scan verified correct, but per-wave private m-streaming starved at
// VGPR=60 (compiler serialized loads; 4 L2 round-trips/chunk on the critical path, 4x traffic).
// R5: m-slice staged chunk-wise (32 rows, hi+lo = 16 KB) into double-buffered LDS shared by 4 waves:
//   - T14 split staging: issue loads(ch+2)->regs at top of iter, ds_write(ch+1) before compute,
//     ONE barrier per chunk; 2-chunk prefetch distance hides HBM/L2 latency.
//   - swizzle (rule 21 both-sides): LDS slots linear, SOURCE col = c ^ (row&15); frag read col =
//     (chk*4+quad) ^ (col&15) -> 4 lanes/16B slot.
//   - scan runs on acc registers (D = M x Q^T: col = lane&15 = query, row = m) as R4; quads
//     partition m mod 16; 2-round shfl_xor tie-aware merge. No per-iter LDS transpose.
__global__ __launch_bounds__(256) void knnpq_mfma(const unsigned short* __restrict__ xhi,
                                                  const unsigned short* __restrict__ xlo,
                                                  const float* __restrict__ sqh,
                                                  const unsigned short* __restrict__ whi,
                                                  const unsigned short* __restrict__ wlo,
                                                  float* __restrict__ pd,
                                                  int* __restrict__ pi,
                                                  float* __restrict__ p,
                                                  unsigned short* __restrict__ q) {
    // [buf][plane][32 rows][16 slots of 16B]: 2*2*32*256 B = 32 KB
    __shared__ __align__(16) unsigned short aS[16384];

    const int tid = threadIdx.x;
    const int b  = blockIdx.x;          // batch fastest -> XCD k serves batch k (L2 affinity)
    const int zr = blockIdx.z;
    const int sub = zr >> 1;            // 0..3 within role
    const int wv = tid >> 6, lane = tid & 63;
    const int quad = lane >> 4, col = lane & 15;
    const int koff = quad * 8;
    const size_t xb = (size_t)b * NPTS * CHN;

    if (zr & 1) {
        // ---------------- pq path: 256n x 32o per block, acc[4][2] per wave (R15-proven) ----------------
        const int nt = blockIdx.y >> 2;
        const int ot = ((blockIdx.y & 3) << 2) | sub;                 // 0..15
        const int nbase = nt * 256 + wv * 64;
        const int obase = ot * 32;                                    // row in Bcat [512]

        f32x4 acc[4][2];
#pragma unroll
        for (int i = 0; i < 4; ++i)
#pragma unroll
            for (int j = 0; j < 2; ++j) acc[i][j] = (f32x4)0.f;

        for (int chk = 0; chk < 4; ++chk) {
            short8 ah[4], al[4];
#pragma unroll
            for (int i = 0; i < 4; ++i) {
                size_t g = xb + (size_t)(nbase + i * 16 + col) * CHN + chk * 32 + koff;
                ah[i] = *(const short8*)&xhi[g];
                al[i] = *(const short8*)&xlo[g];
            }
#pragma unroll
            for (int j = 0; j < 2; ++j) {
                size_t g = (size_t)(obase + j * 16 + col) * CHN + chk * 32 + koff;
                short8 bh = *(const short8*)&whi[g];
                short8 bl = *(const short8*)&wlo[g];
#pragma unroll
                for (int i = 0; i < 4; ++i) {
                    acc[i][j] = __builtin_amdgcn_mfma_f32_16x16x32_bf16(ah[i], bh, acc[i][j], 0, 0, 0);
                    acc[i][j] = __builtin_amdgcn_mfma_f32_16x16x32_bf16(ah[i], bl, acc[i][j], 0, 0, 0);
                    acc[i][j] = __builtin_amdgcn_mfma_f32_16x16x32_bf16(al[i], bh, acc[i][j], 0, 0, 0);
                }
            }
        }
#pragma unroll
        for (int i = 0; i < 4; ++i)
#pragma unroll
            for (int j = 0; j < 2; ++j) {
                int oc = (obase + j * 16 + col) & 255;
#pragma unroll
                for (int r = 0; r < 4; ++r) {
                    int n = nbase + i * 16 + quad * 4 + r;
                    size_t off = (size_t)(b * NPTS + n) * NOUT + oc;
                    if (ot < 8) p[off] = acc[i][j][r];
                    else        q[off] = f2bf(acc[i][j][r]);
                }
            }
        return;
    }

    // ---------------- knn path ----------------
    const int q0 = blockIdx.y * 64, ms = sub;
    const int msbase = ms * 512;
    const int myq = q0 + wv * 16 + col;           // this lane's query (D col = lane&15)

    // query B-frags, both planes, resident in 32 VGPRs
    short8 qh[4], ql[4];
    {
        const unsigned short* qrh = xhi + xb + (size_t)myq * CHN + koff;
        const unsigned short* qrl = xlo + xb + (size_t)myq * CHN + koff;
#pragma unroll
        for (int chk = 0; chk < 4; ++chk) {
            qh[chk] = *(const short8*)(qrh + chk * 32);
            ql[chk] = *(const short8*)(qrl + chk * 32);
        }
    }

    float dl[KNN]; int il[KNN];
#pragma unroll
    for (int k = 0; k < KNN; ++k) { dl[k] = FLT_MAX; il[k] = 0; }

    // scan insert: strict < (candidates arrive in ascending m -> ties keep earlier idx)
    auto ins = [&](float v, int idx) {
        if (v < dl[KNN - 1]) {
            bool c0b = v < dl[0];
#pragma unroll
            for (int k = KNN - 1; k >= 1; --k) {
                bool sh   = v < dl[k - 1];
                bool here = v < dl[k];
                float nd = sh ? dl[k - 1] : (here ? v : dl[k]);
                int   ni = sh ? il[k - 1] : (here ? idx : il[k]);
                dl[k] = nd; il[k] = ni;
            }
            if (c0b) { dl[0] = v; il[0] = idx; }
        }
    };
    // merge insert: tie-aware (smaller m-idx wins on equal value)
    auto ins2 = [&](float v, int idx) {
        if ((v < dl[KNN - 1]) || (v == dl[KNN - 1] && idx < il[KNN - 1])) {
            bool c0b = (v < dl[0]) || (v == dl[0] && idx < il[0]);
#pragma unroll
            for (int k = KNN - 1; k >= 1; --k) {
                bool sh   = (v < dl[k - 1]) || (v == dl[k - 1] && idx < il[k - 1]);
                bool here = (v < dl[k])     || (v == dl[k]     && idx < il[k]);
                float nd = sh ? dl[k - 1] : (here ? v : dl[k]);
                int   ni = sh ? il[k - 1] : (here ? idx : il[k]);
                dl[k] = nd; il[k] = ni;
            }
            if (c0b) { dl[0] = v; il[0] = idx; }
        }
    };

    // ---- staging setup: slot s = t*256+tid; p=t>>1, row=(t&1)*16+(tid>>4), c=tid&15 ----
    // LDS dest linear (s*16); SOURCE col = c ^ (row&15)  [row&15 == tid>>4 for both t-parities]
    const unsigned short* gsrc[4];
    {
        const int rA = tid >> 4;                       // 0..15
        const int sc8 = ((tid & 15) ^ rA) << 3;        // swizzled source col * 8 elements
#pragma unroll
        for (int t = 0; t < 4; ++t) {
            const unsigned short* pl = (t >= 2) ? xlo : xhi;
            gsrc[t] = pl + xb + (size_t)(msbase + ((t & 1) << 4) + rA) * CHN + sc8;
        }
    }
    short8 stv[4];
    auto stage_load = [&](int ch) {
#pragma unroll
        for (int t = 0; t < 4; ++t)
            stv[t] = *(const short8*)(gsrc[t] + (size_t)ch * (32 * CHN));
    };
    auto stage_write = [&](int bf) {
        char* d = (char*)aS + bf * 16384 + tid * 16;
#pragma unroll
        for (int t = 0; t < 4; ++t)
            *(short8*)(d + t * 4096) = stv[t];
    };

    // frag-read constants: byte = buf*16384 + plane*8192 + (i*16+col)*256 + ((chk*4+quad)^col)*16
    const int rowb = col << 8;
    int cofs[4];
#pragma unroll
    for (int chk = 0; chk < 4; ++chk)
        cofs[chk] = (((chk << 2) | quad) ^ col) << 4;
    const float* smb = sqh + b * NPTS + msbase + quad * 4;

    // prologue: ch0 staged, ch1 in regs
    stage_load(0);
    stage_write(0);
    stage_load(1);
    __syncthreads();

    int buf = 0;
    for (int ch = 0; ch < 16; ++ch) {
        if (ch < 15) stage_write(buf ^ 1);     // regs hold ch+1
        if (ch < 14) stage_load(ch + 2);       // prefetch ch+2 into regs

        const char* ab = (const char*)aS + buf * 16384;
        float4 s0 = *(const float4*)(smb + ch * 32);
        float4 s1 = *(const float4*)(smb + ch * 32 + 16);

        f32x4 acc[2];
        acc[0] = (f32x4)0.f; acc[1] = (f32x4)0.f;
#pragma unroll
        for (int chk = 0; chk < 4; ++chk) {
            short8 mh0 = *(const short8*)(ab + rowb + cofs[chk]);
            short8 mh1 = *(const short8*)(ab + 4096 + rowb + cofs[chk]);
            short8 ml0 = *(const short8*)(ab + 8192 + rowb + cofs[chk]);
            short8 ml1 = *(const short8*)(ab + 12288 + rowb + cofs[chk]);
            acc[0] = __builtin_amdgcn_mfma_f32_16x16x32_bf16(mh0, qh[chk], acc[0], 0, 0, 0);
            acc[0] = __builtin_amdgcn_mfma_f32_16x16x32_bf16(mh0, ql[chk], acc[0], 0, 0, 0);
            acc[0] = __builtin_amdgcn_mfma_f32_16x16x32_bf16(ml0, qh[chk], acc[0], 0, 0, 0);
            acc[1] = __builtin_amdgcn_mfma_f32_16x16x32_bf16(mh1, qh[chk], acc[1], 0, 0, 0);
            acc[1] = __builtin_amdgcn_mfma_f32_16x16x32_bf16(mh1, ql[chk], acc[1], 0, 0, 0);
            acc[1] = __builtin_amdgcn_mfma_f32_16x16x32_bf16(ml1, qh[chk], acc[1], 0, 0, 0);
        }

        // scan directly on acc: m = msbase + ch*32 + i*16 + quad*4 + r
        {
            float d0 = s0.x - acc[0][0], d1 = s0.y - acc[0][1];
            float d2 = s0.z - acc[0][2], d3 = s0.w - acc[0][3];
            float mn4 = fminf(fminf(d0, d1), fminf(d2, d3));
            if (mn4 < dl[KNN - 1]) {
                int ib = msbase + ch * 32 + quad * 4;
                ins(d0, ib); ins(d1, ib + 1); ins(d2, ib + 2); ins(d3, ib + 3);
            }
            d0 = s1.x - acc[1][0]; d1 = s1.y - acc[1][1];
            d2 = s1.z - acc[1][2]; d3 = s1.w - acc[1][3];
            mn4 = fminf(fminf(d0, d1), fminf(d2, d3));
            if (mn4 < dl[KNN - 1]) {
                int ib = msbase + ch * 32 + 16 + quad * 4;
                ins(d0, ib); ins(d1, ib + 1); ins(d2, ib + 2); ins(d3, ib + 3);
            }
        }
        __syncthreads();
        buf ^= 1;
    }

    // cross-quad merge: quads partition m mod 16; 2 butterfly rounds leave full top-9 in every lane
#pragma unroll
    for (int rd = 0; rd < 2; ++rd) {
        const int xm = 16 << rd;
        float pv[KNN]; int pix[KNN];
#pragma unroll
        for (int k = 0; k < KNN; ++k) {
            pv[k]  = __shfl_xor(dl[k], xm, 64);
            pix[k] = __shfl_xor(il[k], xm, 64);
        }
#pragma unroll
        for (int k = 0; k < KNN; ++k) ins2(pv[k], pix[k]);
    }

    if (quad == 0) {
        size_t ob = ((size_t)(b * NPTS + myq) * 4 + ms) * KNN;
#pragma unroll
        for (int k = 0; k < KNN; ++k) {
            pd[ob + k] = dl[k];
            pi[ob + k] = il[k];
        }
    }
}

// ---------------- kernel 3: merge FUSED + BN stats + packed bf16 (hmax,hmin); 512 thr (R3) ---------------
__global__ __launch_bounds__(512) void stats2_kernel(const float* __restrict__ p,
                                                     const unsigned short* __restrict__ q,
                                                     const float* __restrict__ pd,
                                                     const int* __restrict__ pi,
                                                     float* __restrict__ stats,
                                                     unsigned int* __restrict__ hmm) {
    __shared__ int idx_s[16 * KNN];
    const int b = blockIdx.x, n0 = blockIdx.y * 16;
    const int tid = threadIdx.x;
    const int o = tid & 255, half = tid >> 8;
    if (tid < 16) {
        size_t g = (size_t)(b * NPTS + n0 + tid) * 36;
        const float* d = pd + g;
        const int*   i = pi + g;
        int p0 = 0, p1 = 0, p2 = 0, p3 = 0;
#pragma unroll
        for (int k = 0; k < KNN; ++k) {
            float v0 = (p0 < KNN) ? d[p0]      : FLT_MAX;
            float v1 = (p1 < KNN) ? d[9 + p1]  : FLT_MAX;
            float v2 = (p2 < KNN) ? d[18 + p2] : FLT_MAX;
            float v3 = (p3 < KNN) ? d[27 + p3] : FLT_MAX;
            float best = v0; int sel = 0;
            if (v1 < best) { best = v1; sel = 1; }
            if (v2 < best) { best = v2; sel = 2; }
            if (v3 < best) { best = v3; sel = 3; }
            int idx;
            if      (sel == 0) { idx = i[p0];      p0++; }
            else if (sel == 1) { idx = i[9 + p1];  p1++; }
            else if (sel == 2) { idx = i[18 + p2]; p2++; }
            else               { idx = i[27 + p3]; p3++; }
            idx_s[tid * KNN + k] = idx;
        }
    }
    __syncthreads();
    const unsigned short* qb = q + (size_t)b * NPTS * NOUT + o;
    float s = 0.f, ss = 0.f;
    const int qbase = half * 8;
    for (int qq = 0; qq < 8; qq += 2) {
        const int qi = qbase + qq;
        size_t off0 = (size_t)(b * NPTS + n0 + qi) * NOUT + o;
        size_t off1 = off0 + NOUT;
        float pv0 = p[off0], pv1 = p[off1];
        float h0[KNN], h1[KNN];
#pragma unroll
        for (int k = 0; k < KNN; ++k)
            h0[k] = bf2f(qb[(size_t)idx_s[qi * KNN + k] * NOUT]);
#pragma unroll
        for (int k = 0; k < KNN; ++k)
            h1[k] = bf2f(qb[(size_t)idx_s[(qi + 1) * KNN + k] * NOUT]);
        float mx0 = -FLT_MAX, mn0 = FLT_MAX, mx1 = -FLT_MAX, mn1 = FLT_MAX;
#pragma unroll
        for (int k = 0; k < KNN; ++k) {
            float a = pv0 + h0[k], c = pv1 + h1[k];
            s += a + c; ss += a * a + c * c;
            mx0 = fmaxf(mx0, a); mn0 = fminf(mn0, a);
            mx1 = fmaxf(mx1, c); mn1 = fminf(mn1, c);
        }
        hmm[off0] = ((unsigned int)f2bf(mx0) << 16) | f2bf(mn0);
        hmm[off1] = ((unsigned int)f2bf(mx1) << 16) | f2bf(mn1);
    }
    atomicAdd(&stats[b * 512 + o], s);
    atomicAdd(&stats[b * 512 + NOUT + o], ss);
}

// ---------------- kernel 4: normalize + relu + max_k, transposed store; 512 thr (R3) ----------------
__global__ __launch_bounds__(512) void final_kernel(const unsigned int* __restrict__ hmm,
                                                    const float* __restrict__ stats,
                                                    const float* __restrict__ gamma,
                                                    const float* __restrict__ beta,
                                                    float* __restrict__ out) {
    __shared__ float tr[256 * 17];
    const int b = blockIdx.x, n0 = blockIdx.y * 16;
    const int tid = threadIdx.x;
    const int o = tid & 255, qh = tid >> 8;
    float sum = 0.f, sumsq = 0.f;
#pragma unroll
    for (int i = 0; i < 8; ++i) {
        sum   += stats[i * 512 + o];
        sumsq += stats[i * 512 + NOUT + o];
    }
    const float inv = 1.f / (float)TOTCNT;
    float mean = sum * inv;
    float var  = sumsq * inv - mean * mean;
    float g    = gamma[o] / sqrtf(var + 1e-5f);
    float bet  = beta[o];
    const bool pos = (g >= 0.f);
#pragma unroll
    for (int qq = 0; qq < 8; ++qq) {
        const int qi = qh * 8 + qq;
        size_t off = (size_t)(b * NPTS + n0 + qi) * NOUT + o;
        unsigned int w = hmm[off];
        float v = bf2f(pos ? (unsigned short)(w >> 16) : (unsigned short)(w & 0xFFFFu));
        float hn = (v - mean) * g + bet;
        tr[o * 17 + qi] = fmaxf(hn, 0.f);
    }
    __syncthreads();
    int oo = tid >> 4, qq = tid & 15;    // oo 0..31
    for (int pass = 0; pass < 8; ++pass) {
        int o_ = pass * 32 + oo;
        out[((size_t)b * NOUT + o_) * NPTS + n0 + qq] = tr[o_ * 17 + qq];
    }
}

extern "C" void kernel_launch(void* const* d_in, const int* in_sizes, int n_in,
                              void* d_out, int out_size, void* d_ws, size_t ws_size,
                              hipStream_t stream) {
    (void)in_sizes; (void)n_in; (void)out_size; (void)ws_size;
    const float* x     = (const float*)d_in[0];
    const float* W     = (const float*)d_in[1];
    const float* gamma = (const float*)d_in[2];
    const float* beta  = (const float*)d_in[3];
    float* out = (float*)d_out;

    char* ws = (char*)d_ws;
    float*          p     = (float*)ws;                                   // 16 MB fp32
    unsigned short* q     = (unsigned short*)(ws + (16u << 20));          // 8 MB bf16
    unsigned short* xhi   = (unsigned short*)(ws + (24u << 20));          // 4 MB
    unsigned short* xlo   = (unsigned short*)(ws + (28u << 20));          // 4 MB
    unsigned int*   hmm   = (unsigned int*)(ws + (32u << 20));            // 16 MB
    unsigned short* whi   = (unsigned short*)(ws + (48u << 20));          // 128 KB
    unsigned short* wlo   = (unsigned short*)(ws + (48u << 20) + 131072); // 128 KB
    float*          pd    = (float*)(ws + (49u << 20));                   // 2.25 MB
    int*            pi    = (int*)  (ws + (52u << 20));                   // 2.25 MB
    float*          sqh   = (float*)(ws + (55u << 20));                   // 64 KB
    float*          stats = (float*)(ws + (55u << 20) + 65536);           // 16 KB

    prep_kernel  <<<dim3(8, 33),    256, 0, stream>>>(x, W, xhi, xlo, whi, wlo, sqh, stats);
    knnpq_mfma   <<<dim3(8, 32, 8), 256, 0, stream>>>(xhi, xlo, sqh, whi, wlo, pd, pi, p, q);
    stats2_kernel<<<dim3(8, 128),   512, 0, stream>>>(p, q, pd, pi, stats, hmm);
    final_kernel <<<dim3(8, 128),   512, 0, stream>>>(hmm, stats, gamma, beta, out);
}